// Round 6
// baseline (95.770 us; speedup 1.0000x reference)
//
#include <hip/hip_runtime.h>
#include <stdint.h>

#define NPTS 8192
#define BATCH 4
#define QBLK 1024   // queries per block (8 tiles of 32 per wave x 4 waves)
#define JCH 512     // refs per LDS chunk
#define JBLK 2      // chunks per block -> 1024 refs per block
#define NJX (NPTS / (JCH * JBLK))  // 8 jx slices

typedef __attribute__((ext_vector_type(8))) short bf16x8;   // 8 bf16 = 4 VGPRs
typedef __attribute__((ext_vector_type(16))) float f32x16;  // 32x32 MFMA acc

struct Accum {
  float l1sum;
  float count[BATCH];
  float minsum[8];  // [dir*4+b]
  float pad[3];
};

__device__ __forceinline__ unsigned short f2bf(float x) {  // RNE fp32->bf16
  union { float f; unsigned u; } v; v.f = x;
  unsigned r = v.u + 0x7FFFu + ((v.u >> 16) & 1u);
  return (unsigned short)(r >> 16);
}
__device__ __forceinline__ float bf2f(unsigned short h) {
  union { float f; unsigned u; } v; v.u = ((unsigned)h) << 16;
  return v.f;
}

using as1_t = __attribute__((address_space(1))) const unsigned int;
using as3_t = __attribute__((address_space(3))) unsigned int;
__device__ __forceinline__ void lds_load16(const void* g, void* l) {
  __builtin_amdgcn_global_load_lds((as1_t*)g, (as3_t*)l, 16, 0, 0);
}

// Pack layout (fragment order): per 32-point tile T, 64 chunks of 16 B:
// chunk T*64 + lane = K-slots [8*(lane>>5) ..] of point T*32 + (lane&31), so a
// fragment load is lane-consecutive 16 B -> conflict-free, global_load_lds-able.
// A (ref):   k0-3=[-2x_h,-2x_h,-2x_l,-2x_l] k4-7=y k8-11=z k12-14=3-split(norm+pen) k15=0
// B (query): k0-3=[x_h,x_l,x_h,x_l]         k4-7=y k8-11=z k12-14=[1,1,1]          k15=0
// => D[ref m][query n] = (norm_r + pen) - 2 q.r ; query norm + relu applied in
// reduce (relu monotone and qn a per-query constant: both commute with min).
__device__ __forceinline__ void writeA(uint4* P, int T, int n,
                                       float x, float y, float z, float nn) {
  float ax = -2.f * x, ay = -2.f * y, az = -2.f * z;
  unsigned xh = f2bf(ax), xl = f2bf(ax - bf2f(xh));
  unsigned yh = f2bf(ay), yl = f2bf(ay - bf2f(yh));
  unsigned zh = f2bf(az), zl = f2bf(az - bf2f(zh));
  unsigned nh = f2bf(nn);
  float rem = nn - bf2f((unsigned short)nh);
  unsigned nm = f2bf(rem);
  unsigned nl = f2bf(rem - bf2f((unsigned short)nm));
  uint4 h0, h1;
  h0.x = xh | (xh << 16); h0.y = xl | (xl << 16);
  h0.z = yh | (yh << 16); h0.w = yl | (yl << 16);
  h1.x = zh | (zh << 16); h1.y = zl | (zl << 16);
  h1.z = nh | (nm << 16); h1.w = nl;
  P[T * 64 + n] = h0;
  P[T * 64 + 32 + n] = h1;
}
__device__ __forceinline__ void writeB(uint4* P, int T, int n,
                                       float x, float y, float z) {
  unsigned xh = f2bf(x), xl = f2bf(x - bf2f((unsigned short)xh));
  unsigned yh = f2bf(y), yl = f2bf(y - bf2f((unsigned short)yh));
  unsigned zh = f2bf(z), zl = f2bf(z - bf2f((unsigned short)zh));
  const unsigned ONE = 0x3F80u;
  unsigned ux = xh | (xl << 16), uy = yh | (yl << 16), uz = zh | (zl << 16);
  uint4 h0, h1;
  h0.x = ux; h0.y = ux; h0.z = uy; h0.w = uy;
  h1.x = uz; h1.y = uz; h1.z = ONE | (ONE << 16); h1.w = ONE;
  P[T * 64 + n] = h0;
  P[T * 64 + 32 + n] = h1;
}

__global__ __launch_bounds__(256) void prep_kernel(
    const float* __restrict__ pred, const float* __restrict__ target,
    const int* __restrict__ mask, const float* __restrict__ points,
    uint4* __restrict__ Apred, uint4* __restrict__ Aclean,
    uint4* __restrict__ Bclean, uint4* __restrict__ Bpred,
    float* __restrict__ qnClean, float* __restrict__ qnPred,
    float* __restrict__ l1part, Accum* __restrict__ acc) {
  int tid = threadIdx.x;
  int g = blockIdx.x * 256 + tid;  // 128 blocks x 256 = BATCH*NPTS
  if (g < 16) ((float*)acc)[g] = 0.f;  // zero accumulators (read by later nodes only)
  float px = pred[3 * g], py = pred[3 * g + 1], pz = pred[3 * g + 2];
  float tx = target[3 * g], ty = target[3 * g + 1], tz = target[3 * g + 2];
  float ox = points[3 * g], oy = points[3 * g + 1], oz = points[3 * g + 2];
  int m = mask[g];
  float cx = ox + tx, cy = oy + ty, cz = oz + tz;  // clean
  float qx = ox + px, qy = oy + py, qz = oz + pz;  // predicted denoised
  float cn = cx * cx + cy * cy + cz * cz;
  float qn = qx * qx + qy * qy + qz * qz;
  float pen = m ? 0.f : 1e9f;
  qnClean[g] = cn;
  qnPred[g] = qn;
  int T = g >> 5, n = g & 31;
  writeA(Apred, T, n, qx, qy, qz, qn + pen);   // dir0 refs = pred-denoised
  writeA(Aclean, T, n, cx, cy, cz, cn + pen);  // dir1 refs = clean
  writeB(Bclean, T, n, cx, cy, cz);            // dir0 queries = clean
  writeB(Bpred, T, n, qx, qy, qz);             // dir1 queries = pred-denoised

  // per-block L1 partial (summed by final_kernel)
  float fm = (float)m;
  float l1c = fm * (fabsf(px - tx) + fabsf(py - ty) + fabsf(pz - tz)) * (1.f / 3.f);
  for (int off = 32; off; off >>= 1) l1c += __shfl_down(l1c, off);
  __shared__ float pl[4];
  if ((tid & 63) == 0) pl[tid >> 6] = l1c;
  __syncthreads();
  if (tid == 0) l1part[blockIdx.x] = pl[0] + pl[1] + pl[2] + pl[3];
}

// Block = (jx, qy, dir*4+b): 1024 refs x 1024 queries. Refs double-buffered
// through LDS in 2 chunks of 512; queries held in registers (8 frags/wave).
// Writes raw per-jx row mins to a PRIVATE partial slice: no atomics, no fences.
__global__ __launch_bounds__(256) void chamfer_kernel(
    const uint4* __restrict__ Apred, const uint4* __restrict__ Aclean,
    const uint4* __restrict__ Bclean, const uint4* __restrict__ Bpred,
    float* __restrict__ partial) {
  __shared__ uint4 Asm[2][1024];  // 2 x 16 KB
  int z = blockIdx.z, dir = z >> 2, b = z & 3;
  const uint4* __restrict__ Ag = dir ? Aclean : Apred;
  const uint4* __restrict__ Bg = dir ? Bpred : Bclean;
  int jx = blockIdx.x;                 // 0..7 (1024 refs each)
  int qbase = blockIdx.y * QBLK;       // 1024 queries
  int tid = threadIdx.x;

  const uint4* Agp = Ag + (size_t)(b * NPTS + jx * (JBLK * JCH)) * 2;
  // stage chunk 0 (lane-consecutive 16 B: wave-uniform base + lane*16)
#pragma unroll
  for (int it = 0; it < 4; it++)
    lds_load16(Agp + it * 256 + tid, &Asm[0][it * 256 + tid]);

  // query fragments from global (once per wave; coalesced, L2-hot)
  int lane = tid & 63, w = tid >> 6, n = lane & 31;
  const bf16x8* Bb = (const bf16x8*)(Bg + (size_t)(b * NPTS + qbase) * 2);
  bf16x8 bfr[8];
  float acc[8];
#pragma unroll
  for (int q = 0; q < 8; q++) {
    bfr[q] = Bb[(w * 8 + q) * 64 + lane];  // wave owns 8 query tiles (256 queries)
    acc[q] = 1e30f;
  }

  f32x16 zacc = {0.f, 0.f, 0.f, 0.f, 0.f, 0.f, 0.f, 0.f,
                 0.f, 0.f, 0.f, 0.f, 0.f, 0.f, 0.f, 0.f};

#pragma unroll
  for (int jb = 0; jb < JBLK; jb++) {
    __syncthreads();  // drains vmcnt: chunk jb staged (and waves done with jb-1)
    if (jb + 1 < JBLK) {  // prefetch next chunk into the other buffer
      const uint4* An = Agp + (jb + 1) * 1024;
      uint4* dst = &Asm[(jb + 1) & 1][0];
#pragma unroll
      for (int it = 0; it < 4; it++)
        lds_load16(An + it * 256 + tid, dst + it * 256 + tid);
    }
    const bf16x8* Al = (const bf16x8*)Asm[jb & 1];
#pragma unroll 4
    for (int p = 0; p < 16; p++) {  // 16 ref tiles per chunk
      bf16x8 af = Al[p * 64 + lane];
#pragma unroll
      for (int q = 0; q < 8; q++) {
        f32x16 d = __builtin_amdgcn_mfma_f32_32x32x16_bf16(af, bfr[q], zacc, 0, 0, 0);
        // 16 regs = 16 ref rows for this lane's query col -> 8 chained v_min3
        acc[q] = fminf(fminf(d[0], d[1]), acc[q]);
        acc[q] = fminf(fminf(d[2], d[3]), acc[q]);
        acc[q] = fminf(fminf(d[4], d[5]), acc[q]);
        acc[q] = fminf(fminf(d[6], d[7]), acc[q]);
        acc[q] = fminf(fminf(d[8], d[9]), acc[q]);
        acc[q] = fminf(fminf(d[10], d[11]), acc[q]);
        acc[q] = fminf(fminf(d[12], d[13]), acc[q]);
        acc[q] = fminf(fminf(d[14], d[15]), acc[q]);
      }
    }
  }

  // epilogue: combine row halves, plain coalesced store of raw mins
  float* __restrict__ Pq = partial + ((size_t)(z * NJX + jx)) * NPTS + qbase;
#pragma unroll
  for (int q = 0; q < 8; q++) {
    float v = fminf(acc[q], __shfl_xor(acc[q], 32));
    if (lane < 32) Pq[(w * 8 + q) * 32 + n] = v;
  }
}

// 64 blocks: 8 per (dir,b) slice. Fold 8 jx partials per query, add qn, relu,
// mask, wave-reduce, one atomicAdd per block.
__global__ __launch_bounds__(256) void reduce_kernel(
    const int* __restrict__ mask, const float* __restrict__ partial,
    const float* __restrict__ qnClean, const float* __restrict__ qnPred,
    Accum* __restrict__ acc) {
  int slice = blockIdx.x >> 3, sub = blockIdx.x & 7;
  int dir = slice >> 2, bb = slice & 3;
  const float* __restrict__ qn = (dir ? qnPred : qnClean) + bb * NPTS + sub * 1024;
  int t = threadIdx.x;
  const float* __restrict__ P = partial + (size_t)slice * NJX * NPTS + sub * 1024;
  float s = 0.f, c = 0.f;
  for (int i = t; i < 1024; i += 256) {
    float v = P[i];
#pragma unroll
    for (int j = 1; j < NJX; j++) v = fminf(v, P[(size_t)j * NPTS + i]);
    v = fmaxf(v + qn[i], 0.f);
    float m = (float)mask[bb * NPTS + sub * 1024 + i];
    s += m * v;
    c += m;
  }
  for (int off = 32; off; off >>= 1) {
    s += __shfl_down(s, off);
    c += __shfl_down(c, off);
  }
  __shared__ float rs[4], rc[4];
  int wave = t >> 6;
  if ((t & 63) == 0) { rs[wave] = s; rc[wave] = c; }
  __syncthreads();
  if (t == 0) {
    atomicAdd(&acc->minsum[slice], rs[0] + rs[1] + rs[2] + rs[3]);
    if (dir == 0) atomicAdd(&acc->count[bb], rc[0] + rc[1] + rc[2] + rc[3]);
  }
}

__global__ void final_kernel(const Accum* __restrict__ acc,
                             const float* __restrict__ l1part,
                             float* __restrict__ out) {
  int t = threadIdx.x;  // 128
  float l1 = l1part[t];
  for (int off = 32; off; off >>= 1) l1 += __shfl_down(l1, off);
  __shared__ float r[2];
  if ((t & 63) == 0) r[t >> 6] = l1;
  __syncthreads();
  if (t == 0) {
    float l1s = r[0] + r[1];
    float msum = 0.f, cham = 0.f;
#pragma unroll
    for (int b = 0; b < BATCH; b++) {
      msum += acc->count[b];
      cham += (acc->minsum[b] + acc->minsum[4 + b]) / fmaxf(acc->count[b], 1.f);
    }
    out[0] = 0.5f * (l1s / msum + cham * (1.f / BATCH));
  }
}

extern "C" void kernel_launch(void* const* d_in, const int* in_sizes, int n_in,
                              void* d_out, int out_size, void* d_ws, size_t ws_size,
                              hipStream_t stream) {
  const float* pred   = (const float*)d_in[0];
  const float* target = (const float*)d_in[1];
  const int*   mask   = (const int*)d_in[2];
  const float* points = (const float*)d_in[3];
  float* out = (float*)d_out;

  const int NP = BATCH * NPTS;  // 32768
  uint4* Apred  = (uint4*)d_ws;            // 1 MB each
  uint4* Aclean = Apred + NP * 2;
  uint4* Bclean = Aclean + NP * 2;
  uint4* Bpred  = Bclean + NP * 2;
  float* qnClean = (float*)(Bpred + NP * 2);   // 128 KB each
  float* qnPred  = qnClean + NP;
  float* partial = qnPred + NP;                // 8*NJX*NPTS floats = 2 MB
  float* l1part  = partial + 8 * NJX * NPTS;   // 128 floats
  Accum* acc     = (Accum*)(l1part + 128);

  prep_kernel<<<NP / 256, 256, 0, stream>>>(
      pred, target, mask, points, Apred, Aclean, Bclean, Bpred,
      qnClean, qnPred, l1part, acc);

  dim3 grid(NJX, NPTS / QBLK, 2 * BATCH);  // (8,8,8) = 512 blocks
  chamfer_kernel<<<grid, 256, 0, stream>>>(
      Apred, Aclean, Bclean, Bpred, partial);

  reduce_kernel<<<64, 256, 0, stream>>>(mask, partial, qnClean, qnPred, acc);
  final_kernel<<<1, 128, 0, stream>>>(acc, l1part, out);
}